// Round 7
// baseline (248.434 us; speedup 1.0000x reference)
//
#include <hip/hip_runtime.h>
#include <math.h>

// SkipGram negative-sampling loss.
// loss = -( sum_n logsig(t_n . c_n) + logsig( -sum_k t_n . neg_{n,k} ) ) / N
//
// R7: time tracks FETCH_SIZE at a pinned ~3.4 TB/s random-line rate (R4/R5/R6
// evidence). Cut gathered bytes 2x again: tables -> fp8 e4m3 (OCP) via HW
// cvt_pk_fp8_f32 / cvt_pk_f32_fp8, scaled by 256 (power of 2, exactly undone
// after the dot). Rows = 128B; fp8 tables = 25.6 MB, close to aggregate L2.
//
// Layout: 16 lanes per pair (4 pairs/wave); lane owns 8 elems = one uint2
// (8 fp8). Row read = 16 lanes x 8B = 128B contiguous.

#define BLOCK 256
#define GRID  2048
#define WPB   (BLOCK / 64)

typedef float v2f __attribute__((ext_vector_type(2)));

#if defined(__has_builtin)
#if __has_builtin(__builtin_amdgcn_cvt_pk_f32_fp8) && __has_builtin(__builtin_amdgcn_cvt_pk_fp8_f32)
#define HAVE_FP8 1
#endif
#endif
#ifndef HAVE_FP8
#define HAVE_FP8 0
#endif

__device__ __forceinline__ float log_sigmoidf(float x) {
    // stable: min(x,0) - log1p(exp(-|x|))
    return fminf(x, 0.0f) - log1pf(__expf(-fabsf(x)));
}

#if HAVE_FP8

#define SCALE      256.0f                 // 2^8: W*256 ~ +-1, in e4m3 normal range
#define INV_SCALE2 (1.0f / 65536.0f)      // undo scale^2 on the dot (exact)

// ---------------- f32 -> fp8(e4m3, x256) streaming conversion --------------

__global__ __launch_bounds__(256) void cvt_fp8(
        const float* __restrict__ srcA, uint2* __restrict__ dstA, int nA,
        const float* __restrict__ srcB, uint2* __restrict__ dstB, int nB)
{
    const int chunksA = nA >> 3;                 // 8 elems per chunk
    const int total   = chunksA + (nB >> 3);
    for (int i = blockIdx.x * blockDim.x + threadIdx.x; i < total;
         i += gridDim.x * blockDim.x) {
        const float4* s; uint2* d; int j;
        if (i < chunksA) { s = (const float4*)srcA; d = dstA; j = i; }
        else             { s = (const float4*)srcB; d = dstB; j = i - chunksA; }
        const float4 f0 = s[2 * j], f1 = s[2 * j + 1];
        int lo = 0, hi = 0;
        lo = __builtin_amdgcn_cvt_pk_fp8_f32(f0.x * SCALE, f0.y * SCALE, lo, false);
        lo = __builtin_amdgcn_cvt_pk_fp8_f32(f0.z * SCALE, f0.w * SCALE, lo, true);
        hi = __builtin_amdgcn_cvt_pk_fp8_f32(f1.x * SCALE, f1.y * SCALE, hi, false);
        hi = __builtin_amdgcn_cvt_pk_fp8_f32(f1.z * SCALE, f1.w * SCALE, hi, true);
        d[j] = make_uint2((unsigned)lo, (unsigned)hi);
    }
}

// ---------------- main gather kernel, fp8 tables ----------------

__device__ __forceinline__ void dec8(uint2 u, float* o) {
    v2f a = __builtin_amdgcn_cvt_pk_f32_fp8((int)u.x, false);
    v2f b = __builtin_amdgcn_cvt_pk_f32_fp8((int)u.x, true);
    v2f c = __builtin_amdgcn_cvt_pk_f32_fp8((int)u.y, false);
    v2f d = __builtin_amdgcn_cvt_pk_f32_fp8((int)u.y, true);
    o[0] = a.x; o[1] = a.y; o[2] = b.x; o[3] = b.y;
    o[4] = c.x; o[5] = c.y; o[6] = d.x; o[7] = d.y;
}

__global__ __launch_bounds__(BLOCK) void sg_main_fp8(
        const int* __restrict__ tgt,        // [N]
        const int* __restrict__ ctx,        // [N]
        const int* __restrict__ neg,        // [N,5]
        const uint2* __restrict__ Wh,       // [V,16] uint2 (=128 fp8/row)
        const uint2* __restrict__ Wo,       // [V,16] uint2
        float* __restrict__ partials,       // [GRID]
        int N)
{
    const int tid  = threadIdx.x;
    const int lane = tid & 63;
    const int sl   = lane & 15;          // lane within 16-lane group
    const int sub  = lane >> 4;          // group within wave: 0..3
    const int wib  = tid >> 6;
    const int gwave  = blockIdx.x * WPB + wib;
    const int stride = GRID * WPB * 4;

    float acc = 0.0f;

    for (int n = gwave * 4 + sub; n < N; n += stride) {
        const int it = tgt[n];
        const int ic = ctx[n];

        const uint2 tu = Wh[((size_t)it << 4) + sl];
        const uint2 cu = Wo[((size_t)ic << 4) + sl];

        // issue all 5 neg loads before decoding (MLP)
        uint2 eu[5];
        #pragma unroll
        for (int k = 0; k < 5; ++k)
            eu[k] = Wo[((size_t)neg[n * 5 + k] << 4) + sl];

        float t[8], c[8];
        dec8(tu, t);
        dec8(cu, c);

        float p = t[0] * c[0];
        #pragma unroll
        for (int i = 1; i < 8; ++i) p = fmaf(t[i], c[i], p);

        float q = 0.0f;
        #pragma unroll
        for (int k = 0; k < 5; ++k) {
            float e[8];
            dec8(eu[k], e);
            #pragma unroll
            for (int i = 0; i < 8; ++i) q = fmaf(t[i], e[i], q);
        }

        // 16-lane butterfly (serves 4 pairs per instruction)
        #pragma unroll
        for (int off = 8; off; off >>= 1) {
            p += __shfl_xor(p, off, 64);
            q += __shfl_xor(q, off, 64);
        }

        if (sl == 0)
            acc += log_sigmoidf(p * INV_SCALE2) + log_sigmoidf(-q * INV_SCALE2);
    }

    __shared__ float s[BLOCK / 16];
    if (sl == 0) s[tid >> 4] = acc;
    __syncthreads();
    if (tid == 0) {
        float b = 0.0f;
        #pragma unroll
        for (int i = 0; i < BLOCK / 16; ++i) b += s[i];
        partials[blockIdx.x] = b;         // every block writes -> no ws init
    }
}

#endif // HAVE_FP8

// ---------------- f32 fallback (used if ws too small / no fp8 builtins) ----

__device__ __forceinline__ float dot8(float4 a0, float4 a1, float4 b0, float4 b1) {
    float r = a0.x * b0.x;
    r = fmaf(a0.y, b0.y, r); r = fmaf(a0.z, b0.z, r); r = fmaf(a0.w, b0.w, r);
    r = fmaf(a1.x, b1.x, r); r = fmaf(a1.y, b1.y, r); r = fmaf(a1.z, b1.z, r);
    r = fmaf(a1.w, b1.w, r);
    return r;
}

__global__ __launch_bounds__(BLOCK) void sg_main_f32(
        const int* __restrict__ tgt, const int* __restrict__ ctx,
        const int* __restrict__ neg,
        const float* __restrict__ Wh, const float* __restrict__ Wo,
        float* __restrict__ partials, int N)
{
    const int tid  = threadIdx.x;
    const int lane = tid & 63;
    const int sl   = lane & 15;
    const int sub  = lane >> 4;
    const int wib  = tid >> 6;
    const int gwave  = blockIdx.x * WPB + wib;
    const int stride = GRID * WPB * 4;

    const float4* __restrict__ Wh4 = (const float4*)Wh;
    const float4* __restrict__ Wo4 = (const float4*)Wo;

    float acc = 0.0f;
    for (int n = gwave * 4 + sub; n < N; n += stride) {
        const int it = tgt[n];
        const int ic = ctx[n];
        const float4* tp = Wh4 + ((size_t)it << 5);
        const float4* cp = Wo4 + ((size_t)ic << 5);
        const float4 t0 = tp[sl], t1 = tp[sl + 16];
        const float4 c0 = cp[sl], c1 = cp[sl + 16];

        float4 s0 = {0.f, 0.f, 0.f, 0.f};
        float4 s1 = {0.f, 0.f, 0.f, 0.f};
        #pragma unroll
        for (int k = 0; k < 5; ++k) {
            const int in_ = neg[n * 5 + k];
            const float4* ep = Wo4 + ((size_t)in_ << 5);
            const float4 e0 = ep[sl], e1 = ep[sl + 16];
            s0.x += e0.x; s0.y += e0.y; s0.z += e0.z; s0.w += e0.w;
            s1.x += e1.x; s1.y += e1.y; s1.z += e1.z; s1.w += e1.w;
        }

        float p = dot8(t0, t1, c0, c1);
        float q = dot8(t0, t1, s0, s1);
        #pragma unroll
        for (int off = 8; off; off >>= 1) {
            p += __shfl_xor(p, off, 64);
            q += __shfl_xor(q, off, 64);
        }
        if (sl == 0)
            acc += log_sigmoidf(p) + log_sigmoidf(-q);
    }

    __shared__ float s[BLOCK / 16];
    if (sl == 0) s[tid >> 4] = acc;
    __syncthreads();
    if (tid == 0) {
        float b = 0.0f;
        #pragma unroll
        for (int i = 0; i < BLOCK / 16; ++i) b += s[i];
        partials[blockIdx.x] = b;
    }
}

// ---------------- finalize ----------------

__global__ __launch_bounds__(256) void sg_final(
        const float* __restrict__ partials,
        float* __restrict__ out, int nPart, float invN)
{
    __shared__ float s[256];
    float v = 0.0f;
    for (int i = threadIdx.x; i < nPart; i += 256) v += partials[i];
    s[threadIdx.x] = v;
    __syncthreads();
    for (int off = 128; off; off >>= 1) {
        if (threadIdx.x < off) s[threadIdx.x] += s[threadIdx.x + off];
        __syncthreads();
    }
    if (threadIdx.x == 0) out[0] = -s[0] * invN;
}

extern "C" void kernel_launch(void* const* d_in, const int* in_sizes, int n_in,
                              void* d_out, int out_size, void* d_ws, size_t ws_size,
                              hipStream_t stream)
{
    const int*   tgt = (const int*)d_in[0];   // targets_1_pos          [N] int32
    const int*   ctx = (const int*)d_in[1];   // contexts_1_pos         [N] int32
    const int*   neg = (const int*)d_in[2];   // contexts_0_pos_samples [N,5] int32
    const float* Wh  = (const float*)d_in[3]; // W_hidden  [V,128] f32
    const float* Wo  = (const float*)d_in[4]; // W_output  [V,128] f32
    float* out = (float*)d_out;

    const int N    = in_sizes[0];
    const int tblH = in_sizes[3];             // V*D elements
    const int tblO = in_sizes[4];

    float* partials = (float*)d_ws;           // GRID*4 = 8 KB
    const size_t off = 8192;

#if HAVE_FP8
    const size_t need = off + (size_t)tblH + (size_t)tblO;   // 1 B/elem
    if (ws_size >= need) {
        uint2* WhB = (uint2*)((char*)d_ws + off);
        uint2* WoB = WhB + (tblH >> 3);
        cvt_fp8<<<2048, 256, 0, stream>>>(Wh, WhB, tblH, Wo, WoB, tblO);
        sg_main_fp8<<<GRID, BLOCK, 0, stream>>>(tgt, ctx, neg, WhB, WoB,
                                                partials, N);
    } else {
        sg_main_f32<<<GRID, BLOCK, 0, stream>>>(tgt, ctx, neg, Wh, Wo,
                                                partials, N);
    }
#else
    sg_main_f32<<<GRID, BLOCK, 0, stream>>>(tgt, ctx, neg, Wh, Wo,
                                            partials, N);
#endif
    sg_final<<<1, 256, 0, stream>>>(partials, out, GRID, 1.0f / (float)N);
}

// Round 8
// 100.736 us; speedup vs baseline: 2.4662x; 2.4662x over previous
//
#include <hip/hip_runtime.h>
#include <hip/hip_fp16.h>
#include <math.h>

// SkipGram negative-sampling loss.
// loss = -( sum_n logsig(t_n . c_n) + logsig( -sum_k t_n . neg_{n,k} ) ) / N
//
// R8: R7's fp8 path never ran -- __has_builtin(amdgcn builtin) is FALSE in the
// HOST compile pass, so kernel_launch picked the f32 fallback. Fix: host always
// launches the fp8 path; the fp8 FORMAT is chosen inside device code only:
//   - primary: HW e4m3 via v_cvt_pk_fp8_f32 / v_cvt_pk_f32_fp8 (scale 256)
//   - fallback (and host-parse branch): top-8-bits-of-f16 (e5m2) bit trick
// Encoder and decoder switch on the SAME macro -> always self-consistent.
//
// Evidence basis (R4/R5/R6): time tracks gathered bytes at a pinned
// ~3.4 TB/s beyond-L2 rate. fp8 rows = 128B -> gather volume halves vs bf16,
// and the 25.6 MB tables approach aggregate-L2 residency.

#define BLOCK 256
#define GRID  2048
#define WPB   (BLOCK / 64)

#define SCALE      256.0f                 // 2^8: W*256 ~ +-1
#define INV_SCALE2 (1.0f / 65536.0f)      // undo scale^2 on dots (exact)

typedef float v2f __attribute__((ext_vector_type(2)));

// Device-pass-only format selection. Host pass parses the fallback branch.
#if defined(__AMDGCN__) && defined(__has_builtin)
#if __has_builtin(__builtin_amdgcn_cvt_pk_fp8_f32) && __has_builtin(__builtin_amdgcn_cvt_pk_f32_fp8)
#define FP8_HW 1
#endif
#endif
#ifndef FP8_HW
#define FP8_HW 0
#endif

__device__ __forceinline__ float log_sigmoidf(float x) {
    // stable: min(x,0) - log1p(exp(-|x|))
    return fminf(x, 0.0f) - log1pf(__expf(-fabsf(x)));
}

// ---------------- fp8 encode: 4 floats (pre-scaled) -> 4 bytes ----------------

__device__ __forceinline__ unsigned enc4(float a, float b, float c, float d) {
#if FP8_HW
    int r = 0;
    r = __builtin_amdgcn_cvt_pk_fp8_f32(a, b, r, false);   // bytes 0,1
    r = __builtin_amdgcn_cvt_pk_fp8_f32(c, d, r, true);    // bytes 2,3
    return (unsigned)r;
#else
    // e5m2 = RTNE-rounded top byte of f16
    float in[4] = {a, b, c, d};
    unsigned r = 0;
    for (int i = 0; i < 4; ++i) {
        __half h = __float2half(in[i]);
        unsigned hb = (unsigned)__half_as_ushort(h);
        unsigned lo = hb & 0xffu;
        unsigned code = (hb >> 8) + ((lo > 0x80u) || (lo == 0x80u && ((hb >> 8) & 1u)));
        r |= (code & 0xffu) << (8 * i);
    }
    return r;
#endif
}

// ---------------- fp8 decode: uint2 (8 bytes) -> 8 floats ----------------

__device__ __forceinline__ void dec8(uint2 u, float* o) {
#if FP8_HW
    v2f a = __builtin_amdgcn_cvt_pk_f32_fp8((int)u.x, false);
    v2f b = __builtin_amdgcn_cvt_pk_f32_fp8((int)u.x, true);
    v2f c = __builtin_amdgcn_cvt_pk_f32_fp8((int)u.y, false);
    v2f d = __builtin_amdgcn_cvt_pk_f32_fp8((int)u.y, true);
    o[0] = a.x; o[1] = a.y; o[2] = b.x; o[3] = b.y;
    o[4] = c.x; o[5] = c.y; o[6] = d.x; o[7] = d.y;
#else
    unsigned w[2] = {u.x, u.y};
    for (int j = 0; j < 2; ++j)
        for (int i = 0; i < 4; ++i) {
            __half_raw hr;
            hr.x = (unsigned short)(((w[j] >> (8 * i)) & 0xffu) << 8);
            o[4 * j + i] = __half2float(*reinterpret_cast<__half*>(&hr));
        }
#endif
}

// ---------------- f32 -> fp8(x256) streaming conversion ----------------

__global__ __launch_bounds__(256) void cvt_fp8(
        const float* __restrict__ srcA, uint2* __restrict__ dstA, int nA,
        const float* __restrict__ srcB, uint2* __restrict__ dstB, int nB)
{
    const int chunksA = nA >> 3;                 // 8 elems per chunk
    const int total   = chunksA + (nB >> 3);
    for (int i = blockIdx.x * blockDim.x + threadIdx.x; i < total;
         i += gridDim.x * blockDim.x) {
        const float4* s; uint2* d; int j;
        if (i < chunksA) { s = (const float4*)srcA; d = dstA; j = i; }
        else             { s = (const float4*)srcB; d = dstB; j = i - chunksA; }
        const float4 f0 = s[2 * j], f1 = s[2 * j + 1];
        uint2 o;
        o.x = enc4(f0.x * SCALE, f0.y * SCALE, f0.z * SCALE, f0.w * SCALE);
        o.y = enc4(f1.x * SCALE, f1.y * SCALE, f1.z * SCALE, f1.w * SCALE);
        d[j] = o;
    }
}

// ---------------- main gather kernel, fp8 tables ----------------
// 16 lanes per pair (4 pairs/wave); lane owns 8 elems = one uint2 (8 fp8).
// Row read = 16 lanes x 8B = 128B contiguous (2 cache lines).

__global__ __launch_bounds__(BLOCK) void sg_main_fp8(
        const int* __restrict__ tgt,        // [N]
        const int* __restrict__ ctx,        // [N]
        const int* __restrict__ neg,        // [N,5]
        const uint2* __restrict__ Wh,       // [V,16] uint2 (=128 fp8/row)
        const uint2* __restrict__ Wo,       // [V,16] uint2
        float* __restrict__ partials,       // [GRID]
        int N)
{
    const int tid  = threadIdx.x;
    const int lane = tid & 63;
    const int sl   = lane & 15;          // lane within 16-lane group
    const int sub  = lane >> 4;          // group within wave: 0..3
    const int wib  = tid >> 6;
    const int gwave  = blockIdx.x * WPB + wib;
    const int stride = GRID * WPB * 4;

    float acc = 0.0f;

    for (int n = gwave * 4 + sub; n < N; n += stride) {
        const int it = tgt[n];
        const int ic = ctx[n];

        const uint2 tu = Wh[((size_t)it << 4) + sl];
        const uint2 cu = Wo[((size_t)ic << 4) + sl];

        // issue all 5 neg loads before decoding (MLP)
        uint2 eu[5];
        #pragma unroll
        for (int k = 0; k < 5; ++k)
            eu[k] = Wo[((size_t)neg[n * 5 + k] << 4) + sl];

        float t[8], c[8];
        dec8(tu, t);
        dec8(cu, c);

        float p = t[0] * c[0];
        #pragma unroll
        for (int i = 1; i < 8; ++i) p = fmaf(t[i], c[i], p);

        float q = 0.0f;
        #pragma unroll
        for (int k = 0; k < 5; ++k) {
            float e[8];
            dec8(eu[k], e);
            #pragma unroll
            for (int i = 0; i < 8; ++i) q = fmaf(t[i], e[i], q);
        }

        // 16-lane butterfly (serves 4 pairs per instruction)
        #pragma unroll
        for (int off = 8; off; off >>= 1) {
            p += __shfl_xor(p, off, 64);
            q += __shfl_xor(q, off, 64);
        }

        if (sl == 0)
            acc += log_sigmoidf(p * INV_SCALE2) + log_sigmoidf(-q * INV_SCALE2);
    }

    __shared__ float s[BLOCK / 16];
    if (sl == 0) s[tid >> 4] = acc;
    __syncthreads();
    if (tid == 0) {
        float b = 0.0f;
        #pragma unroll
        for (int i = 0; i < BLOCK / 16; ++i) b += s[i];
        partials[blockIdx.x] = b;         // every block writes -> no ws init
    }
}

// ---------------- f32 fallback (only if ws too small; proven R5 kernel) ----

__device__ __forceinline__ float dot8(float4 a0, float4 a1, float4 b0, float4 b1) {
    float r = a0.x * b0.x;
    r = fmaf(a0.y, b0.y, r); r = fmaf(a0.z, b0.z, r); r = fmaf(a0.w, b0.w, r);
    r = fmaf(a1.x, b1.x, r); r = fmaf(a1.y, b1.y, r); r = fmaf(a1.z, b1.z, r);
    r = fmaf(a1.w, b1.w, r);
    return r;
}

__global__ __launch_bounds__(BLOCK) void sg_main_f32(
        const int* __restrict__ tgt, const int* __restrict__ ctx,
        const int* __restrict__ neg,
        const float* __restrict__ Wh, const float* __restrict__ Wo,
        float* __restrict__ partials, int N)
{
    const int tid  = threadIdx.x;
    const int lane = tid & 63;
    const int sl   = lane & 15;
    const int sub  = lane >> 4;
    const int wib  = tid >> 6;
    const int gwave  = blockIdx.x * WPB + wib;
    const int stride = GRID * WPB * 4;

    const float4* __restrict__ Wh4 = (const float4*)Wh;
    const float4* __restrict__ Wo4 = (const float4*)Wo;

    float acc = 0.0f;
    for (int n = gwave * 4 + sub; n < N; n += stride) {
        const int it = tgt[n];
        const int ic = ctx[n];
        const float4* tp = Wh4 + ((size_t)it << 5);
        const float4* cp = Wo4 + ((size_t)ic << 5);
        const float4 t0 = tp[sl], t1 = tp[sl + 16];
        const float4 c0 = cp[sl], c1 = cp[sl + 16];

        float4 s0 = {0.f, 0.f, 0.f, 0.f};
        float4 s1 = {0.f, 0.f, 0.f, 0.f};
        #pragma unroll
        for (int k = 0; k < 5; ++k) {
            const int in_ = neg[n * 5 + k];
            const float4* ep = Wo4 + ((size_t)in_ << 5);
            const float4 e0 = ep[sl], e1 = ep[sl + 16];
            s0.x += e0.x; s0.y += e0.y; s0.z += e0.z; s0.w += e0.w;
            s1.x += e1.x; s1.y += e1.y; s1.z += e1.z; s1.w += e1.w;
        }

        float p = dot8(t0, t1, c0, c1);
        float q = dot8(t0, t1, s0, s1);
        #pragma unroll
        for (int off = 8; off; off >>= 1) {
            p += __shfl_xor(p, off, 64);
            q += __shfl_xor(q, off, 64);
        }
        if (sl == 0)
            acc += log_sigmoidf(p) + log_sigmoidf(-q);
    }

    __shared__ float s[BLOCK / 16];
    if (sl == 0) s[tid >> 4] = acc;
    __syncthreads();
    if (tid == 0) {
        float b = 0.0f;
        #pragma unroll
        for (int i = 0; i < BLOCK / 16; ++i) b += s[i];
        partials[blockIdx.x] = b;
    }
}

// ---------------- finalize ----------------

__global__ __launch_bounds__(256) void sg_final(
        const float* __restrict__ partials,
        float* __restrict__ out, int nPart, float invN)
{
    __shared__ float s[256];
    float v = 0.0f;
    for (int i = threadIdx.x; i < nPart; i += 256) v += partials[i];
    s[threadIdx.x] = v;
    __syncthreads();
    for (int off = 128; off; off >>= 1) {
        if (threadIdx.x < off) s[threadIdx.x] += s[threadIdx.x + off];
        __syncthreads();
    }
    if (threadIdx.x == 0) out[0] = -s[0] * invN;
}

extern "C" void kernel_launch(void* const* d_in, const int* in_sizes, int n_in,
                              void* d_out, int out_size, void* d_ws, size_t ws_size,
                              hipStream_t stream)
{
    const int*   tgt = (const int*)d_in[0];   // targets_1_pos          [N] int32
    const int*   ctx = (const int*)d_in[1];   // contexts_1_pos         [N] int32
    const int*   neg = (const int*)d_in[2];   // contexts_0_pos_samples [N,5] int32
    const float* Wh  = (const float*)d_in[3]; // W_hidden  [V,128] f32
    const float* Wo  = (const float*)d_in[4]; // W_output  [V,128] f32
    float* out = (float*)d_out;

    const int N    = in_sizes[0];
    const int tblH = in_sizes[3];             // V*D elements
    const int tblO = in_sizes[4];

    float* partials = (float*)d_ws;           // GRID*4 = 8 KB
    const size_t off  = 8192;
    const size_t need = off + (size_t)tblH + (size_t)tblO;   // 1 B/elem

    if (ws_size >= need) {
        // NO device-builtin gating here: host always takes the fp8 path.
        uint2* WhB = (uint2*)((char*)d_ws + off);
        uint2* WoB = WhB + (tblH >> 3);
        cvt_fp8<<<2048, 256, 0, stream>>>(Wh, WhB, tblH, Wo, WoB, tblO);
        sg_main_fp8<<<GRID, BLOCK, 0, stream>>>(tgt, ctx, neg, WhB, WoB,
                                                partials, N);
    } else {
        sg_main_f32<<<GRID, BLOCK, 0, stream>>>(tgt, ctx, neg, Wh, Wo,
                                                partials, N);
    }
    sg_final<<<1, 256, 0, stream>>>(partials, out, GRID, 1.0f / (float)N);
}